// Round 3
// baseline (971.555 us; speedup 1.0000x reference)
//
#include <hip/hip_runtime.h>
#include <hip/hip_cooperative_groups.h>

namespace cg = cooperative_groups;

#define N_NODES 100000
#define N_EDGES 1250000
#define D_FEAT  64

#define NPB     64                                   // nodes per fine bin
#define NFB     ((N_NODES + NPB - 1) / NPB)          // 1563 fine bins
#define FBMAX   1280                                 // max entries per bin (mean 800)
#define FBMIN   896                                  // min acceptable cap (+3.4 sigma)
#define OVF_CAP 32768

#define GRID_C  1536                                 // 6 blocks/CU floor
#define THREADS 256
#define STRIDE  (GRID_C * THREADS)                   // 393216

// ---------------------------------------------------------------------------
// shared phase bodies (inlined into both the fused kernel and the fallbacks)
// ---------------------------------------------------------------------------

__device__ __forceinline__ void phaseA_scatter(
        int gtid, const int* __restrict__ idxi, const int* __restrict__ idxj,
        int* __restrict__ gcursor, int* __restrict__ ovfcnt,
        int* __restrict__ ovf, int* __restrict__ binbuf, int fbcap) {
    int dd[4], ss[4];
#pragma unroll
    for (int k = 0; k < 4; ++k) {
        int e = gtid + k * STRIDE;
        if (e < N_EDGES) {
            dd[k] = idxi[e];
            ss[k] = idxj[e];
        } else {
            dd[k] = -1; ss[k] = 0;
        }
    }
#pragma unroll
    for (int k = 0; k < 4; ++k) {
        if (dd[k] >= 0) {
            int fb = dd[k] >> 6;
            int pos = atomicAdd(&gcursor[fb], 1);
            if (pos < fbcap) {
                binbuf[(size_t)fb * fbcap + pos] = ((dd[k] & 63) << 17) | ss[k];
            } else {
                int op = atomicAdd(ovfcnt, 1);
                if (op < OVF_CAP) { ovf[2 * op] = dd[k]; ovf[2 * op + 1] = ss[k]; }
            }
        }
    }
}

// per-bin: LDS counting sort + register-accumulated gather
__device__ __forceinline__ void phaseB_bin(
        int bin, int t, const float* __restrict__ x,
        const int* __restrict__ gcursor, const int* __restrict__ binbuf,
        int fbcap, float* __restrict__ out,
        int* klist, int* srt, int* cnt, int* excl, int* cur) {
    if (t < NPB) cnt[t] = 0;
    __syncthreads();

    int n = gcursor[bin];
    if (n > fbcap) n = fbcap;
    const int* buf = binbuf + (size_t)bin * fbcap;

    for (int i = t; i < n; i += THREADS) {
        int p = buf[i];
        klist[i] = p;
        atomicAdd(&cnt[(p >> 17) & 63], 1);
    }
    __syncthreads();

    if (t < 64) {                       // wave-0 exclusive scan, no barriers
        int v = cnt[t];
        int inc = v;
#pragma unroll
        for (int off = 1; off < 64; off <<= 1) {
            int u = __shfl_up(inc, off, 64);
            if (t >= off) inc += u;
        }
        excl[t] = inc - v;
        cur[t] = 0;
    }
    __syncthreads();

    for (int i = t; i < n; i += THREADS) {
        int p = klist[i];
        int dl = (p >> 17) & 63;
        int pos = excl[dl] + atomicAdd(&cur[dl], 1);
        srt[pos] = p & 0x1FFFF;
    }
    __syncthreads();

    // gather: 4 waves x 4 sub-groups x 16 lanes; 4 float4 row-loads in flight
    int w = t >> 6, lane = t & 63;
    int sub = lane >> 4, c4 = lane & 15;
    const float4* xp = (const float4*)x;
#pragma unroll
    for (int i2 = 0; i2 < 4; ++i2) {
        int dl = w * 16 + sub * 4 + i2;
        int kk = excl[dl];
        int end = kk + cnt[dl];
        float4 acc = make_float4(0.f, 0.f, 0.f, 0.f);
        for (; kk + 4 <= end; kk += 4) {
            int a0 = srt[kk], a1 = srt[kk + 1], a2 = srt[kk + 2], a3 = srt[kk + 3];
            float4 v0 = xp[(size_t)a0 * 16 + c4];
            float4 v1 = xp[(size_t)a1 * 16 + c4];
            float4 v2 = xp[(size_t)a2 * 16 + c4];
            float4 v3 = xp[(size_t)a3 * 16 + c4];
            acc.x += (v0.x + v1.x) + (v2.x + v3.x);
            acc.y += (v0.y + v1.y) + (v2.y + v3.y);
            acc.z += (v0.z + v1.z) + (v2.z + v3.z);
            acc.w += (v0.w + v1.w) + (v2.w + v3.w);
        }
        for (; kk < end; ++kk) {
            float4 v0 = xp[(size_t)srt[kk] * 16 + c4];
            acc.x += v0.x; acc.y += v0.y; acc.z += v0.z; acc.w += v0.w;
        }
        int node = bin * NPB + dl;
        if (node < N_NODES)
            ((float4*)out)[(size_t)node * 16 + c4] = acc;
    }
    __syncthreads();                    // LDS reuse safety for multi-bin blocks
}

// ---------------------------------------------------------------------------
// primary: single cooperative kernel (zero + scatter + gather + fixup)
// ---------------------------------------------------------------------------

__global__ __launch_bounds__(THREADS, 6) void fused_kernel(
        const float* __restrict__ x,
        const int* __restrict__ idxi, const int* __restrict__ idxj,
        int* __restrict__ gcursor, int* __restrict__ ovfcnt,
        int* __restrict__ ovf, int* __restrict__ binbuf, int fbcap,
        float* __restrict__ out) {
    __shared__ int klist[FBMAX];
    __shared__ int srt[FBMAX];
    __shared__ int cnt[NPB];
    __shared__ int excl[NPB];
    __shared__ int cur[NPB];

    cg::grid_group grid = cg::this_grid();
    int t = threadIdx.x;
    int gtid = blockIdx.x * THREADS + t;

    // phase 0: zero cursors
    if (gtid < NFB) gcursor[gtid] = 0;
    if (gtid == NFB) *ovfcnt = 0;
    grid.sync();

    // phase A: fine-bin scatter
    phaseA_scatter(gtid, idxi, idxj, gcursor, ovfcnt, ovf, binbuf, fbcap);
    __threadfence();
    grid.sync();

    // phase B: per-bin sort + gather
    for (int bin = blockIdx.x; bin < NFB; bin += GRID_C)
        phaseB_bin(bin, t, x, gcursor, binbuf, fbcap, out,
                   klist, srt, cnt, excl, cur);

    // phase C: overflow fixup (statistically empty)
    __threadfence();
    grid.sync();
    int novf = *ovfcnt;
    if (novf > OVF_CAP) novf = OVF_CAP;
    if (novf > 0) {
        long long total = (long long)novf * 16;
        for (long long tt = gtid; tt < total; tt += (long long)STRIDE) {
            int e  = (int)(tt >> 4);
            int fo = ((int)tt & 15) << 2;
            int d = ovf[2 * e];
            int s = ovf[2 * e + 1];
            const float4 v = *(const float4*)(x + (size_t)s * D_FEAT + fo);
            float* o = out + (size_t)d * D_FEAT + fo;
            atomicAdd(o + 0, v.x);
            atomicAdd(o + 1, v.y);
            atomicAdd(o + 2, v.z);
            atomicAdd(o + 3, v.w);
        }
    }
}

// ---------------------------------------------------------------------------
// fallback #1: same logic as three ordinary kernels
// ---------------------------------------------------------------------------

__global__ __launch_bounds__(THREADS) void k1_fine_kernel(
        const int* __restrict__ idxi, const int* __restrict__ idxj,
        int* __restrict__ gcursor, int* __restrict__ ovfcnt,
        int* __restrict__ ovf, int* __restrict__ binbuf, int fbcap) {
    int gtid = blockIdx.x * THREADS + threadIdx.x;
    phaseA_scatter(gtid, idxi, idxj, gcursor, ovfcnt, ovf, binbuf, fbcap);
}

__global__ __launch_bounds__(THREADS) void k23_fine_kernel(
        const float* __restrict__ x, const int* __restrict__ gcursor,
        const int* __restrict__ binbuf, int fbcap, float* __restrict__ out) {
    __shared__ int klist[FBMAX];
    __shared__ int srt[FBMAX];
    __shared__ int cnt[NPB];
    __shared__ int excl[NPB];
    __shared__ int cur[NPB];
    phaseB_bin(blockIdx.x, threadIdx.x, x, gcursor, binbuf, fbcap, out,
               klist, srt, cnt, excl, cur);
}

__global__ __launch_bounds__(256) void ovf_fixup_kernel(
        const float* __restrict__ x, const int* __restrict__ ovfcnt,
        const int* __restrict__ ovf, float* __restrict__ out) {
    int n = *ovfcnt;
    if (n > OVF_CAP) n = OVF_CAP;
    long long total = (long long)n * 16;
    long long stride = (long long)gridDim.x * blockDim.x;
    for (long long t = blockIdx.x * blockDim.x + threadIdx.x; t < total; t += stride) {
        int e  = (int)(t >> 4);
        int fo = ((int)t & 15) << 2;
        int d = ovf[2 * e];
        int s = ovf[2 * e + 1];
        const float4 v = *(const float4*)(x + (size_t)s * D_FEAT + fo);
        float* o = out + (size_t)d * D_FEAT + fo;
        atomicAdd(o + 0, v.x);
        atomicAdd(o + 1, v.y);
        atomicAdd(o + 2, v.z);
        atomicAdd(o + 3, v.w);
    }
}

// ---------------------------------------------------------------------------
// fallback #2: atomic scatter-add
// ---------------------------------------------------------------------------

__global__ __launch_bounds__(256) void zero_f4_kernel(float* __restrict__ out, int n4) {
    int i = blockIdx.x * blockDim.x + threadIdx.x;
    if (i < n4) ((float4*)out)[i] = make_float4(0.f, 0.f, 0.f, 0.f);
}

__global__ __launch_bounds__(256) void scatter_add_kernel(const float* __restrict__ x,
                                                          const int* __restrict__ idxi,
                                                          const int* __restrict__ idxj,
                                                          float* __restrict__ out) {
    int t = blockIdx.x * blockDim.x + threadIdx.x;
    int e = t >> 4;
    if (e >= N_EDGES) return;
    int fo = (t & 15) << 2;
    int dst = idxi[e];
    int src = idxj[e];
    const float4 v = *(const float4*)(x + (size_t)src * D_FEAT + fo);
    float* o = out + (size_t)dst * D_FEAT + fo;
    atomicAdd(o + 0, v.x);
    atomicAdd(o + 1, v.y);
    atomicAdd(o + 2, v.z);
    atomicAdd(o + 3, v.w);
}

// ---------------------------------------------------------------------------

extern "C" void kernel_launch(void* const* d_in, const int* in_sizes, int n_in,
                              void* d_out, int out_size, void* d_ws, size_t ws_size,
                              hipStream_t stream) {
    const float* x  = (const float*)d_in[0];
    const int*   ei = (const int*)d_in[1];   // flat (2, N_EDGES)
    const int*   idxi = ei;                  // row 0: destinations
    const int*   idxj = ei + N_EDGES;        // row 1: sources
    float* out = (float*)d_out;

    // ws (ints): gcursor[1600] | ovfcnt+pad[16] | ovf[2*OVF_CAP] | binbuf[NFB*fbcap]
    const size_t HEAD = 1600 + 16 + 2 * (size_t)OVF_CAP;
    long long avail = (long long)(ws_size / sizeof(int)) - (long long)HEAD;
    int fbcap = 0;
    if (avail > 0) {
        long long c = avail / NFB;
        fbcap = (c > FBMAX) ? FBMAX : (int)c;
    }

    if (fbcap >= FBMIN) {
        int* gcursor = (int*)d_ws;
        int* ovfcnt  = gcursor + 1600;
        int* ovf     = ovfcnt + 16;
        int* binbuf  = ovf + 2 * OVF_CAP;

        // --- primary: one cooperative dispatch ---
        void* args[] = {(void*)&x, (void*)&idxi, (void*)&idxj,
                        (void*)&gcursor, (void*)&ovfcnt, (void*)&ovf,
                        (void*)&binbuf, (void*)&fbcap, (void*)&out};
        hipError_t rc = hipLaunchCooperativeKernel((const void*)fused_kernel,
                                                   dim3(GRID_C), dim3(THREADS),
                                                   args, 0, stream);
        if (rc == hipSuccess) return;
        (void)hipGetLastError();             // clear sticky error, fall through

        // --- fallback #1: same logic, three ordinary dispatches ---
        hipMemsetAsync(gcursor, 0, (1600 + 16) * sizeof(int), stream);
        k1_fine_kernel<<<GRID_C, THREADS, 0, stream>>>(idxi, idxj, gcursor,
                                                       ovfcnt, ovf, binbuf, fbcap);
        k23_fine_kernel<<<NFB, THREADS, 0, stream>>>(x, gcursor, binbuf, fbcap, out);
        ovf_fixup_kernel<<<16, 256, 0, stream>>>(x, ovfcnt, ovf, out);
        return;
    }

    // --- fallback #2: atomic scatter-add ---
    int n4 = (N_NODES * D_FEAT) / 4;
    zero_f4_kernel<<<(n4 + 255) / 256, 256, 0, stream>>>(out, n4);
    long long total_threads = (long long)N_EDGES * 16;
    scatter_add_kernel<<<(int)((total_threads + 255) / 256), 256, 0, stream>>>(x, idxi, idxj, out);
}

// Round 4
// 136.382 us; speedup vs baseline: 7.1238x; 7.1238x over previous
//
#include <hip/hip_runtime.h>

#define N_NODES 100000
#define N_EDGES 1250000
#define D_FEAT  64

#define NPB     256                          // nodes per bin
#define NBINS   ((N_NODES + NPB - 1) / NPB)  // 391
#define BCAP    4096                         // entries per bin (mean 3196, +16 sigma)
#define EPB     4096                         // edges per k1 block
#define K1B     ((N_EDGES + EPB - 1) / EPB)  // 306
#define OVF_CAP 32768

// =============== k1: LDS-staged counting-sort binning ===============
// Block-local counting sort by bin (391 bins of 256 nodes), then
// run-coalesced dense writes of packed (dloc<<17 | src) into per-bin slabs.
// Global cursor atomics are one-per-bin-per-block from CONSECUTIVE lanes
// (lane-merged at the line level) -- never per-edge random-lane atomics
// (round-3 post-mortem: those serialize at ~70ns per line op = 900us).
__global__ __launch_bounds__(512) void k1_bin_kernel(
        const int* __restrict__ idxi, const int* __restrict__ idxj,
        int* __restrict__ gcursor, int* __restrict__ ovfcnt,
        int* __restrict__ ovf, int* __restrict__ binbuf) {
    __shared__ int hist[NBINS + 1];
    __shared__ int runstart[NBINS + 1];
    __shared__ int gbase[NBINS];
    __shared__ int cur[NBINS];
    __shared__ int staged[EPB];               // 16 KB
    __shared__ unsigned short sbin[EPB];      // 8 KB
    int t = threadIdx.x;
    if (t <= NBINS) hist[t] = 0;
    __syncthreads();

    int base = blockIdx.x * EPB;
    int n = N_EDGES - base; if (n > EPB) n = EPB;

    int d[8], s[8], bn[8];
#pragma unroll
    for (int j = 0; j < 8; ++j) {             // issue all loads first (MLP)
        int i = t + j * 512;
        if (i < n) { d[j] = idxi[base + i]; s[j] = idxj[base + i]; }
        else       { d[j] = -1; s[j] = 0; }
    }
#pragma unroll
    for (int j = 0; j < 8; ++j) {
        bn[j] = (d[j] >= 0) ? (d[j] >> 8) : -1;
        if (bn[j] >= 0) atomicAdd(&hist[bn[j]], 1);
    }
    __syncthreads();

    // single-wave exclusive scan over 391 bins, 7 bins/lane, no barriers inside
    if (t < 64) {
        int h[7];
        int sum = 0;
#pragma unroll
        for (int q = 0; q < 7; ++q) {
            int b = t * 7 + q;
            h[q] = (b < NBINS) ? hist[b] : 0;
            sum += h[q];
        }
        int inc = sum;
#pragma unroll
        for (int off = 1; off < 64; off <<= 1) {
            int u = __shfl_up(inc, off, 64);
            if (t >= off) inc += u;
        }
        int ex = inc - sum;
#pragma unroll
        for (int q = 0; q < 7; ++q) {
            int b = t * 7 + q;
            if (b < NBINS) runstart[b] = ex;
            ex += h[q];
        }
    }
    __syncthreads();

    if (t < NBINS) {
        int h = hist[t];
        gbase[t] = h ? atomicAdd(&gcursor[t], h) : 0;   // consecutive lanes
        cur[t] = 0;
    }
    __syncthreads();

#pragma unroll
    for (int j = 0; j < 8; ++j) {
        if (bn[j] >= 0) {
            int idx = runstart[bn[j]] + atomicAdd(&cur[bn[j]], 1);
            staged[idx] = ((d[j] & 255) << 17) | s[j];
            sbin[idx] = (unsigned short)bn[j];
        }
    }
    __syncthreads();

    for (int i = t; i < n; i += 512) {
        int b = sbin[i];
        int p = staged[i];
        int tgt = gbase[b] + (i - runstart[b]);
        if (tgt < BCAP) {
            binbuf[b * BCAP + tgt] = p;
        } else {
            int op = atomicAdd(ovfcnt, 1);
            if (op < OVF_CAP) { ovf[2 * op] = b * NPB + (p >> 17); ovf[2 * op + 1] = p & 0x1FFFF; }
        }
    }
}

// =============== k23: fused per-bin sort + high-MLP gather ===============
// One block (1024 thr) per 256-node bin. Register-staged counting sort into
// a 16KB LDS list (wave-0 shuffle scan), then gather: each 16-lane sub-group
// owns 4 nodes serially with a 4-deep row unroll -> 16 rows (4KB) in flight
// per wave, no cross-lane shuffles, direct coalesced float4 stores.
__global__ __launch_bounds__(1024) void k23_fused_kernel(
        const float* __restrict__ x, const int* __restrict__ gcursor,
        const int* __restrict__ binbuf, float* __restrict__ out) {
    __shared__ int cnt[NPB];
    __shared__ int excl[NPB];
    __shared__ int cur[NPB];
    __shared__ int srt[BCAP];                 // 16 KB sorted source list
    int bin = blockIdx.x;
    int t = threadIdx.x;
    if (t < NPB) cnt[t] = 0;
    __syncthreads();

    int n = gcursor[bin];
    if (n > BCAP) n = BCAP;
    const int* src = binbuf + (size_t)bin * BCAP;

    int p[4];
#pragma unroll
    for (int j = 0; j < 4; ++j) {             // issue all loads first (MLP)
        int i = t + j * 1024;
        p[j] = (i < n) ? src[i] : -1;
    }
#pragma unroll
    for (int j = 0; j < 4; ++j)
        if (p[j] >= 0) atomicAdd(&cnt[p[j] >> 17], 1);
    __syncthreads();

    // single-wave exclusive scan over 256 counters, 4/lane, no barriers inside
    if (t < 64) {
        int b0 = t * 4;
        int h0 = cnt[b0], h1 = cnt[b0 + 1], h2 = cnt[b0 + 2], h3 = cnt[b0 + 3];
        int s01 = h0 + h1;
        int sum = s01 + h2 + h3;
        int inc = sum;
#pragma unroll
        for (int off = 1; off < 64; off <<= 1) {
            int u = __shfl_up(inc, off, 64);
            if (t >= off) inc += u;
        }
        int ex = inc - sum;
        excl[b0]     = ex;
        excl[b0 + 1] = ex + h0;
        excl[b0 + 2] = ex + s01;
        excl[b0 + 3] = ex + s01 + h2;
        cur[b0] = 0; cur[b0 + 1] = 0; cur[b0 + 2] = 0; cur[b0 + 3] = 0;
    }
    __syncthreads();

#pragma unroll
    for (int j = 0; j < 4; ++j) {
        if (p[j] >= 0) {
            int dl = p[j] >> 17;
            int pos = excl[dl] + atomicAdd(&cur[dl], 1);
            srt[pos] = p[j] & 0x1FFFF;
        }
    }
    __syncthreads();

    // gather: wave w, sub-group 'sub' (16 lanes) -> nodes w*16 + sub*4 + 0..3
    int w = t >> 6, lane = t & 63;
    int sub = lane >> 4, c4 = lane & 15;
    const float4* xp = (const float4*)x;
#pragma unroll
    for (int i2 = 0; i2 < 4; ++i2) {
        int dl = w * 16 + sub * 4 + i2;
        int node = bin * NPB + dl;
        int k = excl[dl];
        int end = k + cnt[dl];
        float4 acc = make_float4(0.f, 0.f, 0.f, 0.f);
        for (; k + 4 <= end; k += 4) {
            int a0 = srt[k], a1 = srt[k + 1], a2 = srt[k + 2], a3 = srt[k + 3];
            float4 v0 = xp[(size_t)a0 * 16 + c4];
            float4 v1 = xp[(size_t)a1 * 16 + c4];
            float4 v2 = xp[(size_t)a2 * 16 + c4];
            float4 v3 = xp[(size_t)a3 * 16 + c4];
            acc.x += (v0.x + v1.x) + (v2.x + v3.x);
            acc.y += (v0.y + v1.y) + (v2.y + v3.y);
            acc.z += (v0.z + v1.z) + (v2.z + v3.z);
            acc.w += (v0.w + v1.w) + (v2.w + v3.w);
        }
        for (; k < end; ++k) {
            float4 v0 = xp[(size_t)srt[k] * 16 + c4];
            acc.x += v0.x; acc.y += v0.y; acc.z += v0.z; acc.w += v0.w;
        }
        if (node < N_NODES)
            ((float4*)out)[(size_t)node * 16 + c4] = acc;
    }
}

// Add any overflow edges (statistically none) on top of the gathered output.
__global__ __launch_bounds__(256) void ovf_fixup_kernel(
        const float* __restrict__ x, const int* __restrict__ ovfcnt,
        const int* __restrict__ ovf, float* __restrict__ out) {
    int n = *ovfcnt;
    if (n > OVF_CAP) n = OVF_CAP;
    long long total = (long long)n * 16;
    long long stride = (long long)gridDim.x * blockDim.x;
    for (long long t = blockIdx.x * blockDim.x + threadIdx.x; t < total; t += stride) {
        int e  = (int)(t >> 4);
        int fo = ((int)t & 15) << 2;
        int d = ovf[2 * e];
        int s = ovf[2 * e + 1];
        const float4 v = *(const float4*)(x + (size_t)s * D_FEAT + fo);
        float* o = out + (size_t)d * D_FEAT + fo;
        atomicAdd(o + 0, v.x);
        atomicAdd(o + 1, v.y);
        atomicAdd(o + 2, v.z);
        atomicAdd(o + 3, v.w);
    }
}

// ====================== fallback: atomic scatter-add ======================

__global__ __launch_bounds__(256) void zero_f4_kernel(float* __restrict__ out, int n4) {
    int i = blockIdx.x * blockDim.x + threadIdx.x;
    if (i < n4) ((float4*)out)[i] = make_float4(0.f, 0.f, 0.f, 0.f);
}

__global__ __launch_bounds__(256) void scatter_add_kernel(const float* __restrict__ x,
                                                          const int* __restrict__ idxi,
                                                          const int* __restrict__ idxj,
                                                          float* __restrict__ out) {
    int t = blockIdx.x * blockDim.x + threadIdx.x;
    int e = t >> 4;
    if (e >= N_EDGES) return;
    int fo = (t & 15) << 2;
    int dst = idxi[e];
    int src = idxj[e];
    const float4 v = *(const float4*)(x + (size_t)src * D_FEAT + fo);
    float* o = out + (size_t)dst * D_FEAT + fo;
    atomicAdd(o + 0, v.x);
    atomicAdd(o + 1, v.y);
    atomicAdd(o + 2, v.z);
    atomicAdd(o + 3, v.w);
}

extern "C" void kernel_launch(void* const* d_in, const int* in_sizes, int n_in,
                              void* d_out, int out_size, void* d_ws, size_t ws_size,
                              hipStream_t stream) {
    const float* x  = (const float*)d_in[0];
    const int*   ei = (const int*)d_in[1];   // flat (2, N_EDGES)
    const int*   idxi = ei;                  // row 0: destinations
    const int*   idxj = ei + N_EDGES;        // row 1: sources
    float* out = (float*)d_out;

    // --- primary: counting-sort binning + fused sort/gather ---
    // ws (ints): gcursor[512] | ovfcnt+pad[16] | ovf[2*OVF_CAP] | binbuf[NBINS*BCAP]
    {
        size_t need = (512 + 16 + 2 * (size_t)OVF_CAP +
                       (size_t)NBINS * BCAP) * sizeof(int);
        if (ws_size >= need) {
            int* gcursor = (int*)d_ws;
            int* ovfcnt  = gcursor + 512;
            int* ovf     = ovfcnt + 16;
            int* binbuf  = ovf + 2 * OVF_CAP;

            hipMemsetAsync(gcursor, 0, (512 + 16) * sizeof(int), stream);
            k1_bin_kernel<<<K1B, 512, 0, stream>>>(idxi, idxj, gcursor, ovfcnt, ovf, binbuf);
            k23_fused_kernel<<<NBINS, 1024, 0, stream>>>(x, gcursor, binbuf, out);
            ovf_fixup_kernel<<<16, 256, 0, stream>>>(x, ovfcnt, ovf, out);
            return;
        }
    }

    // --- fallback: atomic scatter-add ---
    int n4 = (N_NODES * D_FEAT) / 4;
    zero_f4_kernel<<<(n4 + 255) / 256, 256, 0, stream>>>(out, n4);
    long long total_threads = (long long)N_EDGES * 16;
    scatter_add_kernel<<<(int)((total_threads + 255) / 256), 256, 0, stream>>>(x, idxi, idxj, out);
}

// Round 5
// 132.586 us; speedup vs baseline: 7.3277x; 1.0286x over previous
//
#include <hip/hip_runtime.h>

#define N_NODES 100000
#define N_EDGES 1250000
#define D_FEAT  64

#define NPB     392                          // nodes per bin
#define NBINS   256                          // exactly one k23 block per CU
#define BCAP    6144                         // entries per bin (mean 4900, +17.8 sigma)
#define EPB     5120                         // edges per k1 block
#define EPT     10                           // edges per thread (512 thr)
#define K1B     ((N_EDGES + EPB - 1) / EPB)  // 245 -> <= 1 block per CU
#define OVF_CAP 32768

// =============== k1: LDS-staged counting-sort binning (245 blocks) ===============
// Block-local counting sort by bin (256 bins of 392 nodes), then run-coalesced
// dense writes of packed (dloc<<17 | src) into per-bin slabs. Mean run = 20
// words (80B). Global cursor atomics: one per bin per block from CONSECUTIVE
// lanes (never per-edge random-lane atomics -- round-3: those cost 900us).
__global__ __launch_bounds__(512) void k1_bin_kernel(
        const int* __restrict__ idxi, const int* __restrict__ idxj,
        int* __restrict__ gcursor, int* __restrict__ ovfcnt,
        int* __restrict__ ovf, int* __restrict__ binbuf) {
    __shared__ int hist[NBINS];
    __shared__ int runstart[NBINS];
    __shared__ int gbase[NBINS];
    __shared__ int cur[NBINS];
    __shared__ int staged[EPB];               // 20 KB
    __shared__ unsigned char sbin[EPB];       // 5 KB
    int t = threadIdx.x;
    if (t < NBINS) hist[t] = 0;
    __syncthreads();

    int base = blockIdx.x * EPB;
    int n = N_EDGES - base; if (n > EPB) n = EPB;

    int d[EPT], s[EPT], bn[EPT];
#pragma unroll
    for (int j = 0; j < EPT; ++j) {           // issue all loads first (MLP)
        int i = t + j * 512;
        if (i < n) { d[j] = idxi[base + i]; s[j] = idxj[base + i]; }
        else       { d[j] = -1; s[j] = 0; }
    }
#pragma unroll
    for (int j = 0; j < EPT; ++j) {
        bn[j] = (d[j] >= 0) ? (d[j] / NPB) : -1;   // magic-mul division
        if (bn[j] >= 0) atomicAdd(&hist[bn[j]], 1);
    }
    __syncthreads();

    // single-wave exclusive scan over 256 bins, 4 bins/lane, no barriers inside
    if (t < 64) {
        int b0 = t * 4;
        int h0 = hist[b0], h1 = hist[b0 + 1], h2 = hist[b0 + 2], h3 = hist[b0 + 3];
        int s01 = h0 + h1;
        int sum = s01 + h2 + h3;
        int inc = sum;
#pragma unroll
        for (int off = 1; off < 64; off <<= 1) {
            int u = __shfl_up(inc, off, 64);
            if (t >= off) inc += u;
        }
        int ex = inc - sum;
        runstart[b0]     = ex;
        runstart[b0 + 1] = ex + h0;
        runstart[b0 + 2] = ex + s01;
        runstart[b0 + 3] = ex + s01 + h2;
    }
    __syncthreads();

    if (t < NBINS) {
        int h = hist[t];
        gbase[t] = h ? atomicAdd(&gcursor[t], h) : 0;   // consecutive lanes
        cur[t] = 0;
    }
    __syncthreads();

#pragma unroll
    for (int j = 0; j < EPT; ++j) {
        if (bn[j] >= 0) {
            int idx = runstart[bn[j]] + atomicAdd(&cur[bn[j]], 1);
            staged[idx] = ((d[j] - bn[j] * NPB) << 17) | s[j];
            sbin[idx] = (unsigned char)bn[j];
        }
    }
    __syncthreads();

    for (int i = t; i < n; i += 512) {
        int b = sbin[i];
        int p = staged[i];
        int tgt = gbase[b] + (i - runstart[b]);
        if (tgt < BCAP) {
            binbuf[b * BCAP + tgt] = p;
        } else {
            int op = atomicAdd(ovfcnt, 1);
            if (op < OVF_CAP) { ovf[2 * op] = b * NPB + (p >> 17); ovf[2 * op + 1] = p & 0x1FFFF; }
        }
    }
}

// =============== k23: fused per-bin sort + high-MLP gather (256 blocks) ===============
// One 1024-thread block per CU, each owning one 392-node bin: perfectly uniform
// work. Register-staged counting sort into a 24.6KB LDS list (wave-0 shuffle
// scan, 7 bins/lane), then gather: each 16-lane sub-group owns 6-7 nodes
// serially with a 4-deep row unroll -> 16 rows (4KB) in flight per wave, no
// shuffles, direct coalesced float4 stores. Overflow fixup folded in (owner
// block scans the statistically-empty ovf list after its own writeout).
__global__ __launch_bounds__(1024) void k23_fused_kernel(
        const float* __restrict__ x, const int* __restrict__ gcursor,
        const int* __restrict__ binbuf, const int* __restrict__ ovfcnt,
        const int* __restrict__ ovf, float* __restrict__ out) {
    __shared__ int cnt[NPB];
    __shared__ int excl[NPB];
    __shared__ int cur[NPB];
    __shared__ int srt[BCAP];                 // 24.6 KB sorted source list
    int bin = blockIdx.x;
    int t = threadIdx.x;
    if (t < NPB) cnt[t] = 0;
    __syncthreads();

    int n = gcursor[bin];
    if (n > BCAP) n = BCAP;
    const int* src = binbuf + (size_t)bin * BCAP;

    int p[6];
#pragma unroll
    for (int j = 0; j < 6; ++j) {             // issue all loads first (MLP)
        int i = t + j * 1024;
        p[j] = (i < n) ? src[i] : -1;
    }
#pragma unroll
    for (int j = 0; j < 6; ++j)
        if (p[j] >= 0) atomicAdd(&cnt[p[j] >> 17], 1);
    __syncthreads();

    // single-wave exclusive scan over 392 counters, 7/lane, no barriers inside
    if (t < 64) {
        int h[7];
        int sum = 0;
#pragma unroll
        for (int q = 0; q < 7; ++q) {
            int b = t * 7 + q;
            h[q] = (b < NPB) ? cnt[b] : 0;
            sum += h[q];
        }
        int inc = sum;
#pragma unroll
        for (int off = 1; off < 64; off <<= 1) {
            int u = __shfl_up(inc, off, 64);
            if (t >= off) inc += u;
        }
        int ex = inc - sum;
#pragma unroll
        for (int q = 0; q < 7; ++q) {
            int b = t * 7 + q;
            if (b < NPB) { excl[b] = ex; cur[b] = 0; }
            ex += h[q];
        }
    }
    __syncthreads();

#pragma unroll
    for (int j = 0; j < 6; ++j) {
        if (p[j] >= 0) {
            int dl = p[j] >> 17;
            int pos = excl[dl] + atomicAdd(&cur[dl], 1);
            srt[pos] = p[j] & 0x1FFFF;
        }
    }
    __syncthreads();

    // gather: 64 sub-groups of 16 lanes; sub-group sg -> nodes sg, sg+64, ...
    int sg = t >> 4, c4 = t & 15;
    const float4* xp = (const float4*)x;
    for (int i2 = 0; i2 < 7; ++i2) {
        int dl = sg + (i2 << 6);
        if (dl >= NPB) break;
        int node = bin * NPB + dl;
        int k = excl[dl];
        int end = k + cnt[dl];
        float4 acc = make_float4(0.f, 0.f, 0.f, 0.f);
        for (; k + 4 <= end; k += 4) {
            int a0 = srt[k], a1 = srt[k + 1], a2 = srt[k + 2], a3 = srt[k + 3];
            float4 v0 = xp[(size_t)a0 * 16 + c4];
            float4 v1 = xp[(size_t)a1 * 16 + c4];
            float4 v2 = xp[(size_t)a2 * 16 + c4];
            float4 v3 = xp[(size_t)a3 * 16 + c4];
            acc.x += (v0.x + v1.x) + (v2.x + v3.x);
            acc.y += (v0.y + v1.y) + (v2.y + v3.y);
            acc.z += (v0.z + v1.z) + (v2.z + v3.z);
            acc.w += (v0.w + v1.w) + (v2.w + v3.w);
        }
        for (; k < end; ++k) {
            float4 v0 = xp[(size_t)srt[k] * 16 + c4];
            acc.x += v0.x; acc.y += v0.y; acc.z += v0.z; acc.w += v0.w;
        }
        if (node < N_NODES)
            ((float4*)out)[(size_t)node * 16 + c4] = acc;
    }

    // folded overflow fixup: owner block adds any of ITS overflow edges on top
    // of its own just-written rows (fence orders the stores before the atomics).
    __syncthreads();
    int novf = *ovfcnt;
    if (novf > 0) {
        __threadfence();
        if (novf > OVF_CAP) novf = OVF_CAP;
        int lo = bin * NPB;
        for (int e = t; e < novf; e += 1024) {
            int dnode = ovf[2 * e];
            if ((unsigned)(dnode - lo) < NPB && dnode < N_NODES) {
                int snode = ovf[2 * e + 1];
                const float* vsrc = x + (size_t)snode * D_FEAT;
                float* o = out + (size_t)dnode * D_FEAT;
                for (int f = 0; f < D_FEAT; ++f) atomicAdd(o + f, vsrc[f]);
            }
        }
    }
}

// ====================== fallback: atomic scatter-add ======================

__global__ __launch_bounds__(256) void zero_f4_kernel(float* __restrict__ out, int n4) {
    int i = blockIdx.x * blockDim.x + threadIdx.x;
    if (i < n4) ((float4*)out)[i] = make_float4(0.f, 0.f, 0.f, 0.f);
}

__global__ __launch_bounds__(256) void scatter_add_kernel(const float* __restrict__ x,
                                                          const int* __restrict__ idxi,
                                                          const int* __restrict__ idxj,
                                                          float* __restrict__ out) {
    int t = blockIdx.x * blockDim.x + threadIdx.x;
    int e = t >> 4;
    if (e >= N_EDGES) return;
    int fo = (t & 15) << 2;
    int dst = idxi[e];
    int src = idxj[e];
    const float4 v = *(const float4*)(x + (size_t)src * D_FEAT + fo);
    float* o = out + (size_t)dst * D_FEAT + fo;
    atomicAdd(o + 0, v.x);
    atomicAdd(o + 1, v.y);
    atomicAdd(o + 2, v.z);
    atomicAdd(o + 3, v.w);
}

extern "C" void kernel_launch(void* const* d_in, const int* in_sizes, int n_in,
                              void* d_out, int out_size, void* d_ws, size_t ws_size,
                              hipStream_t stream) {
    const float* x  = (const float*)d_in[0];
    const int*   ei = (const int*)d_in[1];   // flat (2, N_EDGES)
    const int*   idxi = ei;                  // row 0: destinations
    const int*   idxj = ei + N_EDGES;        // row 1: sources
    float* out = (float*)d_out;

    // --- primary: counting-sort binning + fused sort/gather/fixup ---
    // ws (ints): gcursor[256] | ovfcnt+pad[16] | ovf[2*OVF_CAP] | binbuf[NBINS*BCAP]
    {
        size_t need = (256 + 16 + 2 * (size_t)OVF_CAP +
                       (size_t)NBINS * BCAP) * sizeof(int);
        if (ws_size >= need) {
            int* gcursor = (int*)d_ws;
            int* ovfcnt  = gcursor + 256;
            int* ovf     = ovfcnt + 16;
            int* binbuf  = ovf + 2 * OVF_CAP;

            hipMemsetAsync(gcursor, 0, (256 + 16) * sizeof(int), stream);
            k1_bin_kernel<<<K1B, 512, 0, stream>>>(idxi, idxj, gcursor, ovfcnt, ovf, binbuf);
            k23_fused_kernel<<<NBINS, 1024, 0, stream>>>(x, gcursor, binbuf, ovfcnt, ovf, out);
            return;
        }
    }

    // --- fallback: atomic scatter-add ---
    int n4 = (N_NODES * D_FEAT) / 4;
    zero_f4_kernel<<<(n4 + 255) / 256, 256, 0, stream>>>(out, n4);
    long long total_threads = (long long)N_EDGES * 16;
    scatter_add_kernel<<<(int)((total_threads + 255) / 256), 256, 0, stream>>>(x, idxi, idxj, out);
}